// Round 6
// baseline (313.040 us; speedup 1.0000x reference)
//
#include <hip/hip_runtime.h>

// Problem constants (B=4, N=2048 fixed by the reference).
#define NN 2048
#define BB 4
#define PARAM_G 0.125f
#define VIRUS_DEATH 8e-5f

// Workspace layout (float indices):
//   [P_OFF,   P_OFF+32*8192)  partial colsums: [tile p][b][j], p in [0,32)
//   [CS_OFF,  CS_OFF+8192)    colsum[b*N+j] = sum_i F_nm[b,i,j]
//   [FAI_OFF, FAI_OFF+4)      fai[b]  (atomic target, zeroed; 32 atomics total)
//   [TAU_OFF, TAU_OFF+4)      tau[b]
#define P_OFF   0
#define CS_OFF  (32 * 8192)
#define FAI_OFF (CS_OFF + 8192)
#define TAU_OFF (FAI_OFF + 4)

// ---------------------------------------------------------------------------
// Stage A: per-row-tile partial column sums of mob (diag zeroed). NO atomics —
// each block owns a disjoint partial vector. grid (32 tiles of 64 rows,
// 2 col-halves, B) = 256 blocks. unroll 16 -> 16 outstanding 16B loads/lane.
__global__ __launch_bounds__(256) void k_colA(const float* __restrict__ mob,
                                              float* __restrict__ ws) {
    int t  = threadIdx.x;
    int i0 = blockIdx.x * 64;
    int j  = blockIdx.y * 1024 + t * 4;          // global column of this thread
    int b  = blockIdx.z;
    const float* base = mob + ((size_t)b * NN + i0) * NN + j;
    float4 acc = make_float4(0.f, 0.f, 0.f, 0.f);
    #pragma unroll 16
    for (int r = 0; r < 64; ++r) {
        float4 v = *(const float4*)(base + (size_t)r * NN);
        unsigned d = (unsigned)((i0 + r) - j);   // diag: i == j+d, d in [0,4)
        if (d < 4u) ((float*)&v)[d] = 0.0f;
        acc.x += v.x; acc.y += v.y; acc.z += v.z; acc.w += v.w;
    }
    *(float4*)(ws + P_OFF + blockIdx.x * 8192 + b * NN + j) = acc;
}

// ---------------------------------------------------------------------------
// Stage B: reduce the 32 partials -> colsum; fai[b] (one atomic per block);
// tau[b] = sum(S+I+R) in the first block of each batch. grid 32, block 256.
__global__ __launch_bounds__(256) void k_colB(const float* __restrict__ SIR,
                                              float* ws) {
    int t = threadIdx.x;
    int g = blockIdx.x * 256 + t;                // b*N + j over [0, 8192)
    int b = g >> 11;
    float s = 0.f;
    #pragma unroll
    for (int p = 0; p < 32; ++p) s += ws[P_OFF + p * 8192 + g];
    ws[CS_OFF + g] = s;
    // fai[b]: block is entirely within one b (2048/256 = 8 blocks per batch).
    float f = s;
    for (int off = 32; off; off >>= 1) f += __shfl_down(f, off);
    __shared__ float red[4];
    if ((t & 63) == 0) red[t >> 6] = f;
    __syncthreads();
    if (t == 0) atomicAdd(&ws[FAI_OFF + b], red[0] + red[1] + red[2] + red[3]);
    // tau[b]: first block of each batch only (uniform branch).
    if ((blockIdx.x & 7) == 0) {
        float accT = 0.f;
        #pragma unroll
        for (int k = 0; k < 8; ++k) {
            int n = k * 256 + t;
            float4 sv = *(const float4*)(SIR + ((size_t)b * NN + n) * 4);
            accT += sv.x + sv.y + sv.z;
        }
        for (int off = 32; off; off >>= 1) accT += __shfl_down(accT, off);
        __shared__ float red2[4];
        if ((t & 63) == 0) red2[t >> 6] = accT;
        __syncthreads();
        if (t == 0) ws[TAU_OFF + b] = red2[0] + red2[1] + red2[2] + red2[3];
    }
}

// ---------------------------------------------------------------------------
// K2: heavy pass + fused epilogue. One row per WAVE, 4 rows/block ->
// grid (N/4, B) = 2048 blocks (~6/CU by LDS, up to 24 waves/CU for TLP).
// Per row i: write arrive2[b,i,j,{0,1}] = {sps_m, P} as wave-contiguous 1KB
// float4 stores (full 128B lines), shuffle-reduce rowdot_X = sum_j F*X, then
// lane 0 computes the per-node Ht_SIR / arrive1 epilogue.
__global__ __launch_bounds__(256) void k_main(const float* __restrict__ mob,
                                              const float* __restrict__ sps,
                                              const float* __restrict__ SIR,
                                              const float* __restrict__ param_b,
                                              const float* __restrict__ contact,
                                              const float* __restrict__ nb,
                                              const float* __restrict__ nd,
                                              const float* __restrict__ ws,
                                              float* __restrict__ out0,
                                              float* __restrict__ out1,
                                              float* __restrict__ out2) {
    __shared__ __align__(16) float sS[NN];
    __shared__ __align__(16) float sI[NN];
    __shared__ __align__(16) float sR[NN];
    int t = threadIdx.x;
    int b = blockIdx.y;
    for (int j = t; j < NN; j += 256) {
        float4 s = *(const float4*)(SIR + ((size_t)b * NN + j) * 4);
        sS[j] = s.x; sI[j] = s.y; sR[j] = s.z;
    }
    __syncthreads();

    int w = t >> 6, lane = t & 63;
    int i = blockIdx.x * 4 + w;                   // this wave's row
    float m    = ws[FAI_OFF + b] / ws[TAU_OFF + b];
    float invc = 1.0f / ws[CS_OFF + b * NN + i];  // wave-uniform -> broadcast
    size_t rowoff = ((size_t)b * NN + i) * NN;
    const float* mrow = mob + rowoff;
    const float* srow = sps + rowoff;
    float* orow = out2 + rowoff * 2;
    float aS = 0.f, aI = 0.f, aR = 0.f;
    #pragma unroll 8
    for (int iter = 0; iter < 16; ++iter) {
        int j2 = iter * 128 + lane * 2;           // this lane's column pair
        float2 mv = *(const float2*)(mrow + j2);
        float2 sv = *(const float2*)(srow + j2);
        unsigned d = (unsigned)(i - j2);          // diag if d in {0,1}
        if (d == 0u)      { mv.x = 0.f; sv.x = 0.f; }
        else if (d == 1u) { mv.y = 0.f; sv.y = 0.f; }
        float2 xS = *(const float2*)&sS[j2];
        float2 xI = *(const float2*)&sI[j2];
        float2 xR = *(const float2*)&sR[j2];
        aS += mv.x * xS.x + mv.y * xS.y;
        aI += mv.x * xI.x + mv.y * xI.y;
        aR += mv.x * xR.x + mv.y * xR.y;
        *(float4*)(orow + (size_t)j2 * 2) =
            make_float4(sv.x, mv.x * invc, sv.y, mv.y * invc);
    }
    for (int off = 32; off; off >>= 1) {
        aS += __shfl_down(aS, off);
        aI += __shfl_down(aI, off);
        aR += __shfl_down(aR, off);
    }
    if (lane == 0) {                              // fused per-node epilogue
        int g = b * NN + i;
        float4 sir = *(const float4*)(SIR + (size_t)g * 4);
        float S = sir.x, I = sir.y, R = sir.z, Isum = sir.w;
        float pb = param_b[g], ct = contact[g];
        float birth = nb[i], death = nd[i];
        float pop   = S + I + R;
        float pbc   = pb * ct;
        float I_new = S / pop * pbc * I;
        float fS = m * aS * invc, fI = m * aI * invc, fR = m * aR * invc;
        float R_t    = R + PARAM_G * I - death * R - m * R + fR;
        float I_t    = I + I_new - death * I - PARAM_G * I - VIRUS_DEATH * I
                         - m * I + fI;
        float S_t    = S - I_new - death * S + birth * pop - m * S + fS;
        float Isum_t = Isum + I_new;
        float R0     = pbc / (death + PARAM_G + VIRUS_DEATH + m);
        float W      = pbc - death - PARAM_G - VIRUS_DEATH;
        float* o0 = out0 + (size_t)g * 6;
        *(float2*)(o0 + 0) = make_float2(R0, I_new);
        *(float2*)(o0 + 2) = make_float2(S_t, I_t);
        *(float2*)(o0 + 4) = make_float2(R_t, Isum_t);
        *(float4*)(out1 + (size_t)g * 4) = make_float4(W, m, I, pop);
    }
}

// ---------------------------------------------------------------------------
extern "C" void kernel_launch(void* const* d_in, const int* in_sizes, int n_in,
                              void* d_out, int out_size, void* d_ws, size_t ws_size,
                              hipStream_t stream) {
    const float* param_b = (const float*)d_in[0];
    const float* contact = (const float*)d_in[1];
    const float* mob     = (const float*)d_in[2];
    const float* SIR     = (const float*)d_in[3];
    const float* sps     = (const float*)d_in[4];
    const float* nb      = (const float*)d_in[5];
    const float* nd      = (const float*)d_in[6];

    float* out  = (float*)d_out;
    float* out0 = out;                            // Ht_SIR   (B,N,6)
    float* out1 = out + (size_t)BB * NN * 6;      // arrive1  (B,N,4)
    float* out2 = out1 + (size_t)BB * NN * 4;     // arrive2  (B,N,N,2)
    float* ws   = (float*)d_ws;

    // only fai needs zero-init (32 atomics land there)
    (void)hipMemsetAsync(ws + FAI_OFF, 0, 4 * sizeof(float), stream);

    k_colA<<<dim3(32, 2, BB),  256, 0, stream>>>(mob, ws);
    k_colB<<<32,               256, 0, stream>>>(SIR, ws);
    k_main<<<dim3(NN / 4, BB), 256, 0, stream>>>(mob, sps, SIR, param_b, contact,
                                                 nb, nd, ws, out0, out1, out2);
}